// Round 3
// baseline (845.964 us; speedup 1.0000x reference)
//
#include <hip/hip_runtime.h>
#include <stdint.h>

#define N_NODES  (1u << 20)      // 1048576
#define N_EDGES  (1u << 24)      // 16777216
#define N_GRAPHS 64
#define CHUNK    (N_NODES / N_GRAPHS)  // 16384
#define K_HOPS   4

#define NBUCKET  1024            // column buckets
#define CPB      1024            // cols per bucket
#define CAP      18432           // slots per bucket region (λ=16384, +16σ)

#define NBLK_SS  512             // scatter-sort blocks
#define TB_SS    1024            // scatter-sort threads
#define EPT      32              // edges per thread
#define EPB_SS   (TB_SS * EPT)   // 32768 edges per block

#define RBITS    9               // in-bucket row-sort: 512 ranges of 2048 rows
#define NRANGE   (1 << RBITS)
// entry = (row<<10)|col_low (30 bits); range key = entry>>21 = row>>11

// v2 hop decomposition: 64 col-groups (16 buckets = 16384 cols) x 8 row-shards
#define NB2      64              // col-groups
#define BPG      16              // buckets per group
#define FACC2    (BPG * CPB)     // 16384 cols per group
#define RS       8               // row shards (each 64 ranges = 131072 rows)
#define RPS      (NRANGE / RS)   // 64 ranges per shard
#define NBLK_HOP (NB2 * RS)      // 512

typedef uint32_t u32x4 __attribute__((ext_vector_type(4)));
typedef unsigned long long u64x2 __attribute__((ext_vector_type(2)));
typedef float f32x4 __attribute__((ext_vector_type(4)));

__device__ __forceinline__ u32x4 nt_load_u32x4(const uint32_t* p) {
    return __builtin_nontemporal_load((const u32x4*)p);
}
__device__ __forceinline__ u64x2 nt_load_u64x2(const unsigned long long* p) {
    return __builtin_nontemporal_load((const u64x2*)p);
}
__device__ __forceinline__ void nt_store_u32x4(uint32_t* p, u32x4 v) {
    __builtin_nontemporal_store(v, (u32x4*)p);
}
__device__ __forceinline__ void nt_store_f32x4(float* p, f32x4 v) {
    __builtin_nontemporal_store(v, (f32x4*)p);
}
__device__ __forceinline__ f32x4 nt_load_f32x4(const float* p) {
    return __builtin_nontemporal_load((const f32x4*)p);
}

// ---------------------------------------------------------------------------
// Per-block LDS counting sort by bucket, then coalesced run write-out.
__global__ __launch_bounds__(TB_SS, 4)
void scatter_sort_kernel(const void* __restrict__ ei,
                         int* __restrict__ cursor, uint32_t* __restrict__ packed) {
    __shared__ uint32_t sorted[EPB_SS];   // 128 KB
    __shared__ int h[NBUCKET];            // 4 KB
    __shared__ int o[NBUCKET];            // 4 KB (scan, then bumped by scatter)
    __shared__ int ostart[NBUCKET];       // 4 KB (stable run starts)
    __shared__ int gbase[NBUCKET];        // 4 KB
    __shared__ int s_is64;
    int blk = blockIdx.x, tid = threadIdx.x;
    h[tid] = 0;
    size_t base = (size_t)blk * EPB_SS;

    // dtype detection: wave 0 samples odd u32 words across this block's slice.
    if (tid < 64) {
        size_t widx = 2 * base + 2 * (size_t)tid * 512 + 1;
        int nz = (((const uint32_t*)ei)[widx] != 0u);
        unsigned long long m = __ballot(nz);
        if (tid == 0) s_is64 = (m == 0ull) ? 1 : 0;
    }
    __syncthreads();
    int is64 = s_is64;
    uint32_t c_[EPT];

    // Phase A: load cols (non-temporal stream), histogram buckets.
    if (is64) {
        const unsigned long long* cp = (const unsigned long long*)ei + N_EDGES + base;
        #pragma unroll
        for (int it = 0; it < EPT / 4; ++it) {
            size_t i = (size_t)it * (TB_SS * 4) + (size_t)tid * 4;
            u64x2 a = nt_load_u64x2(cp + i);
            u64x2 b2 = nt_load_u64x2(cp + i + 2);
            c_[it * 4 + 0] = (uint32_t)a.x;  c_[it * 4 + 1] = (uint32_t)a.y;
            c_[it * 4 + 2] = (uint32_t)b2.x; c_[it * 4 + 3] = (uint32_t)b2.y;
            atomicAdd(&h[c_[it * 4 + 0] >> 10], 1);
            atomicAdd(&h[c_[it * 4 + 1] >> 10], 1);
            atomicAdd(&h[c_[it * 4 + 2] >> 10], 1);
            atomicAdd(&h[c_[it * 4 + 3] >> 10], 1);
        }
    } else {
        const uint32_t* cp = (const uint32_t*)ei + N_EDGES + base;
        #pragma unroll
        for (int it = 0; it < EPT / 4; ++it) {
            size_t i = (size_t)it * (TB_SS * 4) + (size_t)tid * 4;
            u32x4 a = nt_load_u32x4(cp + i);
            c_[it * 4 + 0] = a.x; c_[it * 4 + 1] = a.y;
            c_[it * 4 + 2] = a.z; c_[it * 4 + 3] = a.w;
            atomicAdd(&h[a.x >> 10], 1);
            atomicAdd(&h[a.y >> 10], 1);
            atomicAdd(&h[a.z >> 10], 1);
            atomicAdd(&h[a.w >> 10], 1);
        }
    }
    __syncthreads();

    // Phase B: wave 0 exclusive-scans h[1024] -> o/ostart.
    if (tid < 64) {
        int b16 = tid * 16;
        int s = 0;
        #pragma unroll
        for (int j = 0; j < 16; ++j) s += h[b16 + j];
        int v = s;
        #pragma unroll
        for (int off = 1; off < 64; off <<= 1) {
            int up = __shfl_up(v, off, 64);
            if (tid >= off) v += up;
        }
        int run = v - s;  // exclusive
        #pragma unroll
        for (int j = 0; j < 16; ++j) {
            o[b16 + j] = run;
            ostart[b16 + j] = run;
            run += h[b16 + j];
        }
    }
    __syncthreads();

    // Per-bucket global reserve (1 atomic per bucket per block).
    gbase[tid] = atomicAdd(&cursor[tid], h[tid]);

    // Phase C: load rows (non-temporal), scatter packed entries into LDS.
    if (is64) {
        const unsigned long long* rp = (const unsigned long long*)ei + base;
        #pragma unroll
        for (int it = 0; it < EPT / 4; ++it) {
            size_t i = (size_t)it * (TB_SS * 4) + (size_t)tid * 4;
            u64x2 a = nt_load_u64x2(rp + i);
            u64x2 b2 = nt_load_u64x2(rp + i + 2);
            uint32_t r0 = (uint32_t)a.x, r1 = (uint32_t)a.y;
            uint32_t r2 = (uint32_t)b2.x, r3 = (uint32_t)b2.y;
            { uint32_t c = c_[it * 4 + 0]; int pos = atomicAdd(&o[c >> 10], 1); sorted[pos] = (r0 << 10) | (c & 1023u); }
            { uint32_t c = c_[it * 4 + 1]; int pos = atomicAdd(&o[c >> 10], 1); sorted[pos] = (r1 << 10) | (c & 1023u); }
            { uint32_t c = c_[it * 4 + 2]; int pos = atomicAdd(&o[c >> 10], 1); sorted[pos] = (r2 << 10) | (c & 1023u); }
            { uint32_t c = c_[it * 4 + 3]; int pos = atomicAdd(&o[c >> 10], 1); sorted[pos] = (r3 << 10) | (c & 1023u); }
        }
    } else {
        const uint32_t* rp = (const uint32_t*)ei + base;
        #pragma unroll
        for (int it = 0; it < EPT / 4; ++it) {
            size_t i = (size_t)it * (TB_SS * 4) + (size_t)tid * 4;
            u32x4 a = nt_load_u32x4(rp + i);
            { uint32_t c = c_[it * 4 + 0]; int pos = atomicAdd(&o[c >> 10], 1); sorted[pos] = (a.x << 10) | (c & 1023u); }
            { uint32_t c = c_[it * 4 + 1]; int pos = atomicAdd(&o[c >> 10], 1); sorted[pos] = (a.y << 10) | (c & 1023u); }
            { uint32_t c = c_[it * 4 + 2]; int pos = atomicAdd(&o[c >> 10], 1); sorted[pos] = (a.z << 10) | (c & 1023u); }
            { uint32_t c = c_[it * 4 + 3]; int pos = atomicAdd(&o[c >> 10], 1); sorted[pos] = (a.w << 10) | (c & 1023u); }
        }
    }
    __syncthreads();

    // Phase D: write-out. Wave w copies buckets [w*64, w*64+64); runs contiguous.
    int wave = tid >> 6, lane = tid & 63;
    for (int k = 0; k < NBUCKET / 16; ++k) {
        int b = wave * (NBUCKET / 16) + k;
        int st = ostart[b];
        int len = o[b] - st;
        int gb = gbase[b];
        if (gb + len > CAP) len = CAP - gb > 0 ? CAP - gb : 0;
        uint32_t* dst = packed + (size_t)b * CAP + gb;
        for (int j = lane; j < len; j += 64)
            dst[j] = sorted[st + j];
    }
}

// ---------------------------------------------------------------------------
// Per-bucket: (a) col histogram -> dinv, z = dinv*x  (b) in-bucket row sort by
// range (row>>11, 512 ranges of 2048 rows) through a 72 KB LDS buffer, with
// the per-range start-offset table exported to global (rstart) for the
// sharded hop kernels.
__global__ __launch_bounds__(512, 2)
void degdinv_sort_kernel(uint32_t* __restrict__ packed, const int* __restrict__ cursor,
                         const float* __restrict__ x,
                         float* __restrict__ dinv, float* __restrict__ z,
                         int* __restrict__ rstart) {
    __shared__ uint32_t sbuf[CAP];      // 72 KB
    __shared__ int h[CPB];              // 4 KB col histogram
    __shared__ int ro[NRANGE];          // 2 KB range hist -> offsets
    int b = blockIdx.x, tid = threadIdx.x;
    for (int l = tid; l < CPB; l += 512) h[l] = 0;
    for (int l = tid; l < NRANGE; l += 512) ro[l] = 0;
    __syncthreads();
    int cnt = cursor[b]; if (cnt > CAP) cnt = CAP;
    uint32_t* seg = packed + (size_t)b * CAP;
    int nq = cnt >> 2;

    // Pass A: col + range histograms (plain loads -> L2-resident for pass C).
    for (int g = tid; g < nq; g += 512) {
        u32x4 v = *(const u32x4*)(seg + 4 * (size_t)g);
        atomicAdd(&h[v.x & 1023u], 1); atomicAdd(&ro[v.x >> 21], 1);
        atomicAdd(&h[v.y & 1023u], 1); atomicAdd(&ro[v.y >> 21], 1);
        atomicAdd(&h[v.z & 1023u], 1); atomicAdd(&ro[v.z >> 21], 1);
        atomicAdd(&h[v.w & 1023u], 1); atomicAdd(&ro[v.w >> 21], 1);
    }
    {
        int t = (nq << 2) + tid;
        if (t < cnt) { uint32_t p = seg[t]; atomicAdd(&h[p & 1023u], 1); atomicAdd(&ro[p >> 21], 1); }
    }
    __syncthreads();

    // Pass B: wave 0 exclusive-scans ro[512] in place (8 per lane).
    if (tid < 64) {
        int b8 = tid * 8;
        int s = 0;
        #pragma unroll
        for (int j = 0; j < 8; ++j) s += ro[b8 + j];
        int v = s;
        #pragma unroll
        for (int off = 1; off < 64; off <<= 1) {
            int up = __shfl_up(v, off, 64);
            if (tid >= off) v += up;
        }
        int run = v - s;  // exclusive
        #pragma unroll
        for (int j = 0; j < 8; ++j) { int c = ro[b8 + j]; ro[b8 + j] = run; run += c; }
    }
    __syncthreads();

    // Export range-start table BEFORE pass C bumps ro.
    for (int l = tid; l < NRANGE; l += 512)
        rstart[(size_t)b * NRANGE + l] = ro[l];
    __syncthreads();

    // Pass C: re-read (L2-hot), scatter into LDS by range.
    for (int g = tid; g < nq; g += 512) {
        u32x4 v = *(const u32x4*)(seg + 4 * (size_t)g);
        { int p = atomicAdd(&ro[v.x >> 21], 1); sbuf[p] = v.x; }
        { int p = atomicAdd(&ro[v.y >> 21], 1); sbuf[p] = v.y; }
        { int p = atomicAdd(&ro[v.z >> 21], 1); sbuf[p] = v.z; }
        { int p = atomicAdd(&ro[v.w >> 21], 1); sbuf[p] = v.w; }
    }
    {
        int t = (nq << 2) + tid;
        if (t < cnt) { uint32_t p = seg[t]; int q = atomicAdd(&ro[p >> 21], 1); sbuf[q] = p; }
    }
    __syncthreads();

    // Pass D: coalesced write-back (nt) + dinv/z.
    for (int g = tid; g < nq; g += 512) {
        u32x4 o4;
        o4.x = sbuf[4 * g + 0]; o4.y = sbuf[4 * g + 1];
        o4.z = sbuf[4 * g + 2]; o4.w = sbuf[4 * g + 3];
        nt_store_u32x4(seg + 4 * (size_t)g, o4);
    }
    {
        int t = (nq << 2) + tid;
        if (t < cnt) __builtin_nontemporal_store(sbuf[t], seg + t);
    }
    for (int l = tid; l < CPB; l += 512) {
        int v = b * CPB + l;
        float d = (float)(1.0 / sqrt((double)(h[l] + 1)));  // +1 self loop
        dinv[v] = d;
        z[v] = d * x[v];
    }
}

// ---------------------------------------------------------------------------
// v2 sharded hop: block = (col-group b2 of 16 buckets, row-shard s of 64
// ranges). facc[16384] in LDS (64 KB). Walks the 64 row-ranges; per range the
// 16 bucket runs all gather from one 8 KB z-window (128 lines) -> ~4 entries
// per line -> ~4x fewer L1/TCP misses than the flat hop. s = blockIdx&7 so
// each XCD's blocks (round-robin dispatch) share one 512 KB z-window in L2.
// Output: partial facc -> P[blk][16384] (merged by merge_* kernels).
__global__ __launch_bounds__(512)
void hop_shard_kernel(const uint32_t* __restrict__ packed, const int* __restrict__ cursor,
                      const int* __restrict__ rstart, const float* __restrict__ z,
                      float* __restrict__ P) {
    __shared__ float facc[FACC2];       // 64 KB
    __shared__ int offs[BPG][RPS + 1];  // 16 x 65 run boundaries
    int blk = blockIdx.x, tid = threadIdx.x;
    int s = blk & (RS - 1), b2 = blk >> 3;
    for (int l = tid; l < FACC2; l += 512) facc[l] = 0.0f;
    for (int idx = tid; idx < BPG * (RPS + 1); idx += 512) {
        int bb = idx / (RPS + 1), r = idx - bb * (RPS + 1);
        int b = b2 * BPG + bb;
        int rr = s * RPS + r;
        int v;
        if (rr < NRANGE) v = rstart[(size_t)b * NRANGE + rr];
        else { int c = cursor[b]; v = c > CAP ? CAP : c; }
        offs[bb][r] = v;
    }
    __syncthreads();
    int wave = tid >> 6, lane = tid & 63;
    for (int rr = 0; rr < RPS; ++rr) {
        #pragma unroll
        for (int k = 0; k < 2; ++k) {
            int bb = wave * 2 + k;
            const uint32_t* seg = packed + (size_t)(b2 * BPG + bb) * CAP;
            int st = offs[bb][rr], en = offs[bb][rr + 1];
            for (int j = st + lane; j < en; j += 64) {
                uint32_t e = __builtin_nontemporal_load(seg + j);
                atomicAdd(&facc[(bb << 10) | (e & 1023u)], z[e >> 10]);
            }
        }
    }
    __syncthreads();
    float* Pb = P + (size_t)blk * FACC2;
    for (int l = tid; l < FACC2 / 4; l += 512) {
        f32x4 v;
        v.x = facc[4 * l + 0]; v.y = facc[4 * l + 1];
        v.z = facc[4 * l + 2]; v.w = facc[4 * l + 3];
        nt_store_f32x4(Pb + 4 * l, v);
    }
}

// Merge 8 shard partials + self-loop, apply d^2, write next z.
__global__ __launch_bounds__(512)
void merge_mid_kernel(const float* __restrict__ P, const float* __restrict__ z,
                      const float* __restrict__ dinv, float* __restrict__ out) {
    int i = blockIdx.x * 512 + threadIdx.x;   // float4 index
    int v0 = i << 2;
    int b2 = v0 >> 14, c = v0 & (FACC2 - 1);
    const float* base = P + (size_t)b2 * RS * FACC2 + c;
    f32x4 acc = {0.0f, 0.0f, 0.0f, 0.0f};
    #pragma unroll
    for (int s = 0; s < RS; ++s)
        acc += nt_load_f32x4(base + (size_t)s * FACC2);
    f32x4 zz = *(const f32x4*)(z + v0);
    f32x4 dd = *(const f32x4*)(dinv + v0);
    f32x4 r = dd * dd * (zz + acc);
    *(f32x4*)(out + v0) = r;
}

// Merge partials for the final hop, apply d, and pool per graph chunk
// (chunk g == col-group g since CHUNK == FACC2 == 16384).
__global__ __launch_bounds__(512)
void merge_final_kernel(const float* __restrict__ P, const float* __restrict__ z,
                        const float* __restrict__ dinv, float* __restrict__ gsum) {
    __shared__ double sdata[8];
    int blk = blockIdx.x;
    int g = blk >> 3, part = blk & 7;
    int c0 = part * 2048 + (int)threadIdx.x * 4;
    int v0 = (g << 14) | c0;
    const float* base = P + (size_t)g * RS * FACC2 + c0;
    f32x4 acc = {0.0f, 0.0f, 0.0f, 0.0f};
    #pragma unroll
    for (int s = 0; s < RS; ++s)
        acc += nt_load_f32x4(base + (size_t)s * FACC2);
    f32x4 zz = *(const f32x4*)(z + v0);
    f32x4 dd = *(const f32x4*)(dinv + v0);
    f32x4 val = dd * (zz + acc);
    double sl = (double)val.x + (double)val.y + (double)val.z + (double)val.w;
    #pragma unroll
    for (int off = 32; off > 0; off >>= 1) sl += __shfl_down(sl, off, 64);
    int wave = threadIdx.x >> 6, lane = threadIdx.x & 63;
    if (lane == 0) sdata[wave] = sl;
    __syncthreads();
    if (threadIdx.x == 0) {
        double tot = 0.0;
        #pragma unroll
        for (int w = 0; w < 8; ++w) tot += sdata[w];
        atomicAdd(&gsum[g], (float)tot);
    }
}

// out[g] = W * gsum[g]/CHUNK + b
__global__ void finalize_kernel(const float* __restrict__ gsum,
                                const float* __restrict__ W, const float* __restrict__ b,
                                float* __restrict__ out) {
    int g = threadIdx.x;
    if (g < N_GRAPHS)
        out[g] = (float)((double)W[0] * ((double)gsum[g] / (double)CHUNK) + (double)b[0]);
}

// ---------------------------------------------------------------------------
// v1 kernels (used when ws is too small for the partials buffer).
__global__ __launch_bounds__(512)
void degdinv_kernel(const uint32_t* __restrict__ packed, const int* __restrict__ cursor,
                    const float* __restrict__ x,
                    float* __restrict__ dinv, float* __restrict__ z) {
    __shared__ int h[CPB];
    int b = blockIdx.x, tid = threadIdx.x;
    for (int l = tid; l < CPB; l += 512) h[l] = 0;
    __syncthreads();
    int cnt = cursor[b]; if (cnt > CAP) cnt = CAP;
    const uint32_t* seg = packed + (size_t)b * CAP;
    int nq = cnt >> 2;
    for (int g = tid; g < nq; g += 512) {
        u32x4 v = nt_load_u32x4(seg + g * 4);
        atomicAdd(&h[v.x & 1023u], 1);
        atomicAdd(&h[v.y & 1023u], 1);
        atomicAdd(&h[v.z & 1023u], 1);
        atomicAdd(&h[v.w & 1023u], 1);
    }
    int t = (nq << 2) + tid;
    if (t < cnt) atomicAdd(&h[seg[t] & 1023u], 1);
    __syncthreads();
    for (int l = tid; l < CPB; l += 512) {
        int v = b * CPB + l;
        float d = (float)(1.0 / sqrt((double)(h[l] + 1)));
        dinv[v] = d;
        z[v] = d * x[v];
    }
}

__global__ __launch_bounds__(512)
void hop_kernel(const uint32_t* __restrict__ packed, const int* __restrict__ cursor,
                const float* __restrict__ z, const float* __restrict__ dinv,
                float* __restrict__ out) {
    __shared__ float facc[CPB];
    int b = blockIdx.x, tid = threadIdx.x;
    for (int l = tid; l < CPB; l += 512) facc[l] = 0.0f;
    __syncthreads();
    int cnt = cursor[b]; if (cnt > CAP) cnt = CAP;
    const uint32_t* seg = packed + (size_t)b * CAP;
    int nq = cnt >> 2;
    for (int g = tid; g < nq; g += 512) {
        u32x4 v = nt_load_u32x4(seg + 4 * (size_t)g);
        float z0 = z[v.x >> 10];
        float z1 = z[v.y >> 10];
        float z2 = z[v.z >> 10];
        float z3 = z[v.w >> 10];
        atomicAdd(&facc[v.x & 1023u], z0);
        atomicAdd(&facc[v.y & 1023u], z1);
        atomicAdd(&facc[v.z & 1023u], z2);
        atomicAdd(&facc[v.w & 1023u], z3);
    }
    int t = (nq << 2) + tid;
    if (t < cnt) { uint32_t p = seg[t]; atomicAdd(&facc[p & 1023u], z[p >> 10]); }
    __syncthreads();
    for (int l = tid; l < CPB; l += 512) {
        int v = b * CPB + l;
        float tt = z[v] + facc[l];
        float d = dinv[v];
        out[v] = d * d * tt;
    }
}

__global__ __launch_bounds__(512)
void hop_final_kernel(const uint32_t* __restrict__ packed, const int* __restrict__ cursor,
                      const float* __restrict__ z, const float* __restrict__ dinv,
                      float* __restrict__ gsum) {
    __shared__ float facc[CPB];
    __shared__ double sdata[8];
    int b = blockIdx.x, tid = threadIdx.x;
    for (int l = tid; l < CPB; l += 512) facc[l] = 0.0f;
    __syncthreads();
    int cnt = cursor[b]; if (cnt > CAP) cnt = CAP;
    const uint32_t* seg = packed + (size_t)b * CAP;
    int nq = cnt >> 2;
    for (int g = tid; g < nq; g += 512) {
        u32x4 v = nt_load_u32x4(seg + 4 * (size_t)g);
        float z0 = z[v.x >> 10];
        float z1 = z[v.y >> 10];
        float z2 = z[v.z >> 10];
        float z3 = z[v.w >> 10];
        atomicAdd(&facc[v.x & 1023u], z0);
        atomicAdd(&facc[v.y & 1023u], z1);
        atomicAdd(&facc[v.z & 1023u], z2);
        atomicAdd(&facc[v.w & 1023u], z3);
    }
    int t = (nq << 2) + tid;
    if (t < cnt) { uint32_t p = seg[t]; atomicAdd(&facc[p & 1023u], z[p >> 10]); }
    __syncthreads();
    double s = 0.0;
    for (int l = tid; l < CPB; l += 512) {
        int v = b * CPB + l;
        s += (double)(dinv[v] * (z[v] + facc[l]));
    }
    #pragma unroll
    for (int off = 32; off > 0; off >>= 1) s += __shfl_down(s, off, 64);
    int wave = tid >> 6, lane = tid & 63;
    if (lane == 0) sdata[wave] = s;
    __syncthreads();
    if (tid == 0) {
        double tot = 0.0;
        #pragma unroll
        for (int w = 0; w < 8; ++w) tot += sdata[w];
        atomicAdd(&gsum[b >> 4], (float)tot);
    }
}

// ---------------- fallback (push, atomics) for small ws ---------------------
__global__ void detect_kernel(const uint32_t* __restrict__ ei, int* __restrict__ flag) {
    __shared__ int any_nz;
    if (threadIdx.x == 0) any_nz = 0;
    __syncthreads();
    int nz = 0;
    for (int i = threadIdx.x; i < 32768; i += blockDim.x)
        nz |= (ei[2 * i + 1] != 0u);
    if (nz) atomicOr(&any_nz, 1);
    __syncthreads();
    if (threadIdx.x == 0) flag[0] = any_nz ? 0 : 1;
}

__global__ void zero_int_kernel(int* __restrict__ p) {
    int i = blockIdx.x * blockDim.x + threadIdx.x;
    p[i] = 0;
}

__device__ __forceinline__ int load_idx(const void* ei, int is64, size_t pos) {
    if (is64) return (int)((const unsigned long long*)ei)[pos];
    return ((const int*)ei)[pos];
}

__global__ void count_kernel(const void* __restrict__ ei, const int* __restrict__ flag,
                             int* __restrict__ deg) {
    int e = blockIdx.x * blockDim.x + threadIdx.x;
    int c = load_idx(ei, flag[0], (size_t)N_EDGES + (size_t)e);
    atomicAdd(&deg[c], 1);
}

__global__ void dinv_kernel(const int* __restrict__ deg, float* __restrict__ dinv) {
    int v = blockIdx.x * blockDim.x + threadIdx.x;
    dinv[v] = (float)(1.0 / sqrt((double)(deg[v] + 1)));
}

__global__ void prep_first2_kernel(const float* __restrict__ x, const float* __restrict__ dinv,
                                   float* __restrict__ z, float* __restrict__ acc) {
    int v = blockIdx.x * blockDim.x + threadIdx.x;
    float t = dinv[v] * x[v];
    z[v] = t;
    acc[v] = t;
}

__global__ void prep_mid_kernel(const float* __restrict__ dinv,
                                float* __restrict__ z, float* __restrict__ acc) {
    int v = blockIdx.x * blockDim.x + threadIdx.x;
    float d = dinv[v];
    float t = d * d * acc[v];
    z[v] = t;
    acc[v] = t;
}

__global__ void push_kernel(const void* __restrict__ ei, const int* __restrict__ flag,
                            const float* __restrict__ z, float* __restrict__ acc) {
    int e = blockIdx.x * blockDim.x + threadIdx.x;
    int is64 = flag[0];
    int r, c;
    if (is64) {
        const unsigned long long* p = (const unsigned long long*)ei;
        r = (int)p[e];
        c = (int)p[(size_t)N_EDGES + (size_t)e];
    } else {
        const int* p = (const int*)ei;
        r = p[e];
        c = p[(size_t)N_EDGES + (size_t)e];
    }
    __hip_atomic_fetch_add(&acc[c], z[r], __ATOMIC_RELAXED, __HIP_MEMORY_SCOPE_AGENT);
}

__global__ void final_scale_kernel(const float* __restrict__ dinv,
                                   const float* __restrict__ acc, float* __restrict__ xf) {
    int v = blockIdx.x * blockDim.x + threadIdx.x;
    xf[v] = dinv[v] * acc[v];
}

__global__ void pool_kernel(const float* __restrict__ xf,
                            const float* __restrict__ W, const float* __restrict__ b,
                            float* __restrict__ out) {
    __shared__ double sdata[256];
    int g = blockIdx.x;
    int base = g * CHUNK;
    double s = 0.0;
    for (int i = threadIdx.x; i < CHUNK; i += 256) s += (double)xf[base + i];
    sdata[threadIdx.x] = s;
    __syncthreads();
    for (int off = 128; off > 0; off >>= 1) {
        if (threadIdx.x < off) sdata[threadIdx.x] += sdata[threadIdx.x + off];
        __syncthreads();
    }
    if (threadIdx.x == 0)
        out[g] = (float)((double)W[0] * (sdata[0] / (double)CHUNK) + (double)b[0]);
}

extern "C" void kernel_launch(void* const* d_in, const int* in_sizes, int n_in,
                              void* d_out, int out_size, void* d_ws, size_t ws_size,
                              hipStream_t stream) {
    const float* x = (const float*)d_in[0];
    const void*  ei = d_in[1];
    const float* W = (const float*)d_in[2];
    const float* b = (const float*)d_in[3];
    float* out = (float*)d_out;

    char* ws = (char*)d_ws;
    const size_t MB4 = 4ull << 20;
    const size_t packed_sz = (size_t)NBUCKET * CAP * 4;          // 72 MB
    const size_t rstart_sz = (size_t)NBUCKET * NRANGE * 4;       // 2 MB
    const size_t P_sz      = (size_t)NBLK_HOP * FACC2 * 4;       // 32 MB

    // v2 layout
    size_t off_cursor = 0;                        // 4 KB
    size_t off_gsum   = NBUCKET * 4;              // 256 B
    size_t off_dinv   = off_gsum + 256;           // 4 MB
    size_t off_za     = off_dinv + MB4;           // 4 MB
    size_t off_zb     = off_za + MB4;             // 4 MB
    size_t off_rstart = off_zb + MB4;             // 2 MB
    size_t off_P      = off_rstart + rstart_sz;   // 32 MB
    size_t off_packed2 = off_P + P_sz;            // 72 MB
    size_t needed_v2  = off_packed2 + packed_sz;  // ~118 MB

    // v1 layout (previous round)
    size_t off_packed1 = off_zb + MB4;
    size_t needed_v1   = off_packed1 + packed_sz; // ~84 MB

    const int TB = 256;

    if (ws_size >= needed_v2) {
        int*      cursor = (int*)(ws + off_cursor);
        float*    gsum   = (float*)(ws + off_gsum);
        float*    dinv   = (float*)(ws + off_dinv);
        float*    za     = (float*)(ws + off_za);
        float*    zb     = (float*)(ws + off_zb);
        int*      rstart = (int*)(ws + off_rstart);
        float*    P      = (float*)(ws + off_P);
        uint32_t* packed = (uint32_t*)(ws + off_packed2);

        hipMemsetAsync(ws, 0, NBUCKET * 4 + 256, stream);  // cursor + gsum

        scatter_sort_kernel<<<NBLK_SS, TB_SS, 0, stream>>>(ei, cursor, packed);
        degdinv_sort_kernel<<<NBUCKET, 512, 0, stream>>>(packed, cursor, x, dinv, za, rstart);

        hop_shard_kernel<<<NBLK_HOP, 512, 0, stream>>>(packed, cursor, rstart, za, P);
        merge_mid_kernel<<<N_NODES / 2048, 512, 0, stream>>>(P, za, dinv, zb);

        hop_shard_kernel<<<NBLK_HOP, 512, 0, stream>>>(packed, cursor, rstart, zb, P);
        merge_mid_kernel<<<N_NODES / 2048, 512, 0, stream>>>(P, zb, dinv, za);

        hop_shard_kernel<<<NBLK_HOP, 512, 0, stream>>>(packed, cursor, rstart, za, P);
        merge_mid_kernel<<<N_NODES / 2048, 512, 0, stream>>>(P, za, dinv, zb);

        hop_shard_kernel<<<NBLK_HOP, 512, 0, stream>>>(packed, cursor, rstart, zb, P);
        merge_final_kernel<<<NBLK_HOP, 512, 0, stream>>>(P, zb, dinv, gsum);

        finalize_kernel<<<1, 64, 0, stream>>>(gsum, W, b, out);
    } else if (ws_size >= needed_v1) {
        int*      cursor = (int*)(ws + off_cursor);
        float*    gsum   = (float*)(ws + off_gsum);
        float*    dinv   = (float*)(ws + off_dinv);
        float*    za     = (float*)(ws + off_za);
        float*    zb     = (float*)(ws + off_zb);
        uint32_t* packed = (uint32_t*)(ws + off_packed1);

        hipMemsetAsync(ws, 0, NBUCKET * 4 + 256, stream);

        scatter_sort_kernel<<<NBLK_SS, TB_SS, 0, stream>>>(ei, cursor, packed);
        degdinv_kernel<<<NBUCKET, 512, 0, stream>>>(packed, cursor, x, dinv, za);

        hop_kernel<<<NBUCKET, 512, 0, stream>>>(packed, cursor, za, dinv, zb);
        hop_kernel<<<NBUCKET, 512, 0, stream>>>(packed, cursor, zb, dinv, za);
        hop_kernel<<<NBUCKET, 512, 0, stream>>>(packed, cursor, za, dinv, zb);
        hop_final_kernel<<<NBUCKET, 512, 0, stream>>>(packed, cursor, zb, dinv, gsum);

        finalize_kernel<<<1, 64, 0, stream>>>(gsum, W, b, out);
    } else {
        // Fallback: push-based with atomics.
        int*   flag = (int*)ws;
        float* dinv = (float*)(ws + 256);
        float* za   = (float*)(ws + 256 + MB4);
        float* zb   = (float*)(ws + 256 + 2 * MB4);
        int*   deg  = (int*)(ws + 256 + 3 * MB4);

        detect_kernel<<<1, TB, 0, stream>>>((const uint32_t*)ei, flag);
        zero_int_kernel<<<N_NODES / TB, TB, 0, stream>>>(deg);
        count_kernel<<<N_EDGES / TB, TB, 0, stream>>>(ei, flag, deg);
        dinv_kernel<<<N_NODES / TB, TB, 0, stream>>>(deg, dinv);

        prep_first2_kernel<<<N_NODES / TB, TB, 0, stream>>>(x, dinv, za, zb);
        push_kernel<<<N_EDGES / TB, TB, 0, stream>>>(ei, flag, za, zb);
        for (int h = 1; h < K_HOPS; ++h) {
            prep_mid_kernel<<<N_NODES / TB, TB, 0, stream>>>(dinv, za, zb);
            push_kernel<<<N_EDGES / TB, TB, 0, stream>>>(ei, flag, za, zb);
        }
        final_scale_kernel<<<N_NODES / TB, TB, 0, stream>>>(dinv, zb, za);
        pool_kernel<<<N_GRAPHS, TB, 0, stream>>>(za, W, b, out);
    }
}

// Round 4
// 822.176 us; speedup vs baseline: 1.0289x; 1.0289x over previous
//
#include <hip/hip_runtime.h>
#include <stdint.h>

#define N_NODES  (1u << 20)      // 1048576
#define N_EDGES  (1u << 24)      // 16777216
#define N_GRAPHS 64
#define CHUNK    (N_NODES / N_GRAPHS)  // 16384
#define K_HOPS   4

// ---- shared pass-1 geometry (v1 and v3 paths) ----
#define NBLK_SS  1024            // sort blocks
#define TB_SS    1024            // sort threads
#define EPT      16              // edges per thread
#define EPB_SS   (TB_SS * EPT)   // 16384 edges per block
#define CAP      18432           // slots per segment (λ=16384, +16σ)

// ---- v1 (1024 col-buckets) ----
#define NBUCKET  1024
#define CPB      1024

// ---- v3 (64 col-buckets × 16 row-shards = 1024 tiles) ----
#define NBKT2    64              // col buckets
#define SHARDS   16              // row shards (65536 rows each)
#define NTILE    (NBKT2 * SHARDS)  // 1024 tiles, ~16384 entries each
#define CPB2     16384           // cols per bucket
// entry = (row & 0xFFFF) << 14 | (col & 0x3FFF)   (30 bits)
// tile  = (col >> 14) << 4 | (row >> 16)          (10 bits)
// in-tile sort key = entry >> 21 = row_rel >> 7   (9 bits, 512 ranges)

typedef uint32_t u32x4 __attribute__((ext_vector_type(4)));
typedef unsigned long long u64x2 __attribute__((ext_vector_type(2)));
typedef float f32x4 __attribute__((ext_vector_type(4)));
typedef int i32x4 __attribute__((ext_vector_type(4)));

__device__ __forceinline__ u32x4 nt_load_u32x4(const uint32_t* p) {
    return __builtin_nontemporal_load((const u32x4*)p);
}
__device__ __forceinline__ u64x2 nt_load_u64x2(const unsigned long long* p) {
    return __builtin_nontemporal_load((const u64x2*)p);
}
__device__ __forceinline__ void nt_store_u32x4(uint32_t* p, u32x4 v) {
    __builtin_nontemporal_store(v, (u32x4*)p);
}

// ---------------------------------------------------------------------------
// v3 pass 1: block counting sort of 16384 edges into 1024 (bucket,shard)
// tiles. Rows AND cols loaded up front (key needs both); payload scattered
// from registers. Dtype detected per block via odd u32 words (int64 node idx
// < 2^20 -> odd words all zero).
__global__ __launch_bounds__(TB_SS, 4)
void tile_sort_kernel(const void* __restrict__ ei,
                      int* __restrict__ cursor, uint32_t* __restrict__ packed) {
    __shared__ uint32_t sorted[EPB_SS];   // 64 KB
    __shared__ int h[NTILE];              // 4 KB
    __shared__ int o[NTILE];              // 4 KB
    __shared__ int ostart[NTILE];         // 4 KB
    __shared__ int gbase[NTILE];          // 4 KB
    __shared__ int s_is64;
    int blk = blockIdx.x, tid = threadIdx.x;
    h[tid] = 0;
    size_t base = (size_t)blk * EPB_SS;

    if (tid < 64) {
        size_t widx = 2 * base + 2 * (size_t)tid * (EPB_SS / 64) + 1;
        int nz = (((const uint32_t*)ei)[widx] != 0u);
        unsigned long long m = __ballot(nz);
        if (tid == 0) s_is64 = (m == 0ull) ? 1 : 0;
    }
    __syncthreads();
    int is64 = s_is64;
    uint32_t c_[EPT], r_[EPT];

    // Phase A: load rows+cols (nt stream), histogram tile keys.
    if (is64) {
        const unsigned long long* cp = (const unsigned long long*)ei + N_EDGES + base;
        const unsigned long long* rp = (const unsigned long long*)ei + base;
        #pragma unroll
        for (int it = 0; it < EPT / 4; ++it) {
            size_t i = (size_t)it * (TB_SS * 4) + (size_t)tid * 4;
            u64x2 ca = nt_load_u64x2(cp + i);
            u64x2 cb = nt_load_u64x2(cp + i + 2);
            u64x2 ra = nt_load_u64x2(rp + i);
            u64x2 rb = nt_load_u64x2(rp + i + 2);
            c_[it * 4 + 0] = (uint32_t)ca.x;  c_[it * 4 + 1] = (uint32_t)ca.y;
            c_[it * 4 + 2] = (uint32_t)cb.x;  c_[it * 4 + 3] = (uint32_t)cb.y;
            r_[it * 4 + 0] = (uint32_t)ra.x;  r_[it * 4 + 1] = (uint32_t)ra.y;
            r_[it * 4 + 2] = (uint32_t)rb.x;  r_[it * 4 + 3] = (uint32_t)rb.y;
            #pragma unroll
            for (int j = 0; j < 4; ++j) {
                int k = it * 4 + j;
                atomicAdd(&h[((c_[k] >> 14) << 4) | (r_[k] >> 16)], 1);
            }
        }
    } else {
        const uint32_t* cp = (const uint32_t*)ei + N_EDGES + base;
        const uint32_t* rp = (const uint32_t*)ei + base;
        #pragma unroll
        for (int it = 0; it < EPT / 4; ++it) {
            size_t i = (size_t)it * (TB_SS * 4) + (size_t)tid * 4;
            u32x4 a = nt_load_u32x4(cp + i);
            u32x4 r = nt_load_u32x4(rp + i);
            c_[it * 4 + 0] = a.x; c_[it * 4 + 1] = a.y;
            c_[it * 4 + 2] = a.z; c_[it * 4 + 3] = a.w;
            r_[it * 4 + 0] = r.x; r_[it * 4 + 1] = r.y;
            r_[it * 4 + 2] = r.z; r_[it * 4 + 3] = r.w;
            #pragma unroll
            for (int j = 0; j < 4; ++j) {
                int k = it * 4 + j;
                atomicAdd(&h[((c_[k] >> 14) << 4) | (r_[k] >> 16)], 1);
            }
        }
    }
    __syncthreads();

    // Phase B: wave 0 exclusive-scans h[1024].
    if (tid < 64) {
        int b16 = tid * 16;
        int s = 0;
        #pragma unroll
        for (int j = 0; j < 16; ++j) s += h[b16 + j];
        int v = s;
        #pragma unroll
        for (int off = 1; off < 64; off <<= 1) {
            int up = __shfl_up(v, off, 64);
            if (tid >= off) v += up;
        }
        int run = v - s;
        #pragma unroll
        for (int j = 0; j < 16; ++j) {
            o[b16 + j] = run;
            ostart[b16 + j] = run;
            run += h[b16 + j];
        }
    }
    __syncthreads();

    gbase[tid] = atomicAdd(&cursor[tid], h[tid]);

    // Phase C: scatter packed entries into LDS from registers.
    #pragma unroll
    for (int k = 0; k < EPT; ++k) {
        uint32_t c = c_[k], r = r_[k];
        int key = ((c >> 14) << 4) | (r >> 16);
        int pos = atomicAdd(&o[key], 1);
        sorted[pos] = ((r & 0xFFFFu) << 14) | (c & 0x3FFFu);
    }
    __syncthreads();

    // Phase D: coalesced run write-out.
    int wave = tid >> 6, lane = tid & 63;
    for (int k = 0; k < NTILE / 16; ++k) {
        int b = wave * (NTILE / 16) + k;
        int st = ostart[b];
        int len = o[b] - st;
        int gb = gbase[b];
        if (gb + len > CAP) len = CAP - gb > 0 ? CAP - gb : 0;
        uint32_t* dst = packed + (size_t)b * CAP + gb;
        for (int j = lane; j < len; j += 64)
            dst[j] = sorted[st + j];
    }
}

// ---------------------------------------------------------------------------
// v3 pass 2: per-tile in-LDS counting sort by row (entry>>21, 512 ranges of
// 128 rows) so hop gathers hit ~4 entries per 64B z-line. Fused: per-tile
// col histogram accumulated into global deg[] (coalesced atomics).
// LDS: 72KB sbuf + 64KB col hist + 2KB ranges = 138KB -> 1 block/CU.
__global__ __launch_bounds__(512, 1)
void tile_rowsort_kernel(uint32_t* __restrict__ packed, const int* __restrict__ cursor,
                         int* __restrict__ deg) {
    __shared__ uint32_t sbuf[CAP];      // 72 KB
    __shared__ int h[CPB2];             // 64 KB col histogram
    __shared__ int ro[512];             // 2 KB range offsets
    int t = blockIdx.x, tid = threadIdx.x;
    for (int l = tid; l < CPB2; l += 512) h[l] = 0;
    for (int l = tid; l < 512; l += 512) ro[l] = 0;
    __syncthreads();
    int cnt = cursor[t]; if (cnt > CAP) cnt = CAP;
    uint32_t* seg = packed + (size_t)t * CAP;
    int nq = cnt >> 2;

    // Pass A: col + range histograms (plain loads -> L2-hot for pass C).
    for (int g = tid; g < nq; g += 512) {
        u32x4 v = *(const u32x4*)(seg + 4 * (size_t)g);
        atomicAdd(&h[v.x & 0x3FFFu], 1); atomicAdd(&ro[v.x >> 21], 1);
        atomicAdd(&h[v.y & 0x3FFFu], 1); atomicAdd(&ro[v.y >> 21], 1);
        atomicAdd(&h[v.z & 0x3FFFu], 1); atomicAdd(&ro[v.z >> 21], 1);
        atomicAdd(&h[v.w & 0x3FFFu], 1); atomicAdd(&ro[v.w >> 21], 1);
    }
    {
        int tt = (nq << 2) + tid;
        if (tt < cnt) { uint32_t p = seg[tt]; atomicAdd(&h[p & 0x3FFFu], 1); atomicAdd(&ro[p >> 21], 1); }
    }
    __syncthreads();

    // Pass B: wave 0 scans ro[512]; all threads add col hist into global deg.
    if (tid < 64) {
        int b8 = tid * 8;
        int s = 0;
        #pragma unroll
        for (int j = 0; j < 8; ++j) s += ro[b8 + j];
        int v = s;
        #pragma unroll
        for (int off = 1; off < 64; off <<= 1) {
            int up = __shfl_up(v, off, 64);
            if (tid >= off) v += up;
        }
        int run = v - s;
        #pragma unroll
        for (int j = 0; j < 8; ++j) { int c = ro[b8 + j]; ro[b8 + j] = run; run += c; }
    }
    {
        int dbase = (t >> 4) << 14;   // bucket base col
        for (int l = tid; l < CPB2; l += 512) {
            int hv = h[l];
            if (hv) atomicAdd(&deg[dbase + l], hv);
        }
    }
    __syncthreads();

    // Pass C: re-read (L2-hot), scatter into LDS by range.
    for (int g = tid; g < nq; g += 512) {
        u32x4 v = *(const u32x4*)(seg + 4 * (size_t)g);
        { int p = atomicAdd(&ro[v.x >> 21], 1); sbuf[p] = v.x; }
        { int p = atomicAdd(&ro[v.y >> 21], 1); sbuf[p] = v.y; }
        { int p = atomicAdd(&ro[v.z >> 21], 1); sbuf[p] = v.z; }
        { int p = atomicAdd(&ro[v.w >> 21], 1); sbuf[p] = v.w; }
    }
    {
        int tt = (nq << 2) + tid;
        if (tt < cnt) { uint32_t p = seg[tt]; int q = atomicAdd(&ro[p >> 21], 1); sbuf[q] = p; }
    }
    __syncthreads();

    // Pass D: coalesced write-back (nt).
    for (int g = tid; g < nq; g += 512) {
        u32x4 o4;
        o4.x = sbuf[4 * g + 0]; o4.y = sbuf[4 * g + 1];
        o4.z = sbuf[4 * g + 2]; o4.w = sbuf[4 * g + 3];
        nt_store_u32x4(seg + 4 * (size_t)g, o4);
    }
    {
        int tt = (nq << 2) + tid;
        if (tt < cnt) __builtin_nontemporal_store(sbuf[tt], seg + tt);
    }
}

// dinv = rsqrt(deg+1), z = dinv * x (vectorized).
__global__ __launch_bounds__(512)
void dinvz_kernel(const int* __restrict__ deg, const float* __restrict__ x,
                  float* __restrict__ dinv, float* __restrict__ z) {
    int i = blockIdx.x * 512 + threadIdx.x;
    int v0 = i << 2;
    i32x4 dg = *(const i32x4*)(deg + v0);
    f32x4 xx = *(const f32x4*)(x + v0);
    f32x4 dd, zz;
    dd.x = (float)(1.0 / sqrt((double)(dg.x + 1)));
    dd.y = (float)(1.0 / sqrt((double)(dg.y + 1)));
    dd.z = (float)(1.0 / sqrt((double)(dg.z + 1)));
    dd.w = (float)(1.0 / sqrt((double)(dg.w + 1)));
    zz = dd * xx;
    *(f32x4*)(dinv + v0) = dd;
    *(f32x4*)(z + v0) = zz;
}

// ---------------------------------------------------------------------------
// v3 hop: block = tile (bucket = blk>>4, shard = blk&15). Contiguous sweep of
// the row-sorted tile segment; 64-lane gathers of consecutive entries touch
// ~16 distinct z-lines (4 entries/line density). LDS facc[16384] per bucket;
// write-out via coalesced global atomics into acc[1M]. blk%8 == shard%8 so
// co-dispatched blocks on one XCD share a ~512KB z-window in L2.
__global__ __launch_bounds__(512)
void hop_acc_kernel(const uint32_t* __restrict__ packed, const int* __restrict__ cursor,
                    const float* __restrict__ z, float* __restrict__ acc) {
    __shared__ float facc[CPB2];    // 64 KB
    int t = blockIdx.x, tid = threadIdx.x;
    int shard = t & (SHARDS - 1), bucket = t >> 4;
    for (int l = tid; l < CPB2; l += 512) facc[l] = 0.0f;
    __syncthreads();
    int cnt = cursor[t]; if (cnt > CAP) cnt = CAP;
    const uint32_t* seg = packed + (size_t)t * CAP;
    const float* zs = z + ((size_t)shard << 16);
    int nq = cnt >> 2;
    for (int g = tid; g < nq; g += 512) {
        u32x4 v = *(const u32x4*)(seg + 4 * (size_t)g);
        float z0 = zs[v.x >> 14];
        float z1 = zs[v.y >> 14];
        float z2 = zs[v.z >> 14];
        float z3 = zs[v.w >> 14];
        atomicAdd(&facc[v.x & 0x3FFFu], z0);
        atomicAdd(&facc[v.y & 0x3FFFu], z1);
        atomicAdd(&facc[v.z & 0x3FFFu], z2);
        atomicAdd(&facc[v.w & 0x3FFFu], z3);
    }
    {
        int tt = (nq << 2) + tid;
        if (tt < cnt) { uint32_t p = seg[tt]; atomicAdd(&facc[p & 0x3FFFu], zs[p >> 14]); }
    }
    __syncthreads();
    float* ab = acc + ((size_t)bucket << 14);
    for (int l = tid; l < CPB2; l += 512) {
        float v = facc[l];
        if (v != 0.0f) atomicAdd(&ab[l], v);
    }
}

// merge: zout = d^2 (z + acc), re-zero acc for next hop.
__global__ __launch_bounds__(512)
void merge_mid_kernel(float* __restrict__ acc, const float* __restrict__ z,
                      const float* __restrict__ dinv, float* __restrict__ out) {
    int i = blockIdx.x * 512 + threadIdx.x;
    int v0 = i << 2;
    f32x4 aa = *(const f32x4*)(acc + v0);
    f32x4 zz = *(const f32x4*)(z + v0);
    f32x4 dd = *(const f32x4*)(dinv + v0);
    f32x4 r = dd * dd * (zz + aa);
    *(f32x4*)(out + v0) = r;
    f32x4 zero = {0.0f, 0.0f, 0.0f, 0.0f};
    *(f32x4*)(acc + v0) = zero;
}

// final merge fused with pooling: sum d*(z+acc) per 16384-col graph chunk.
__global__ __launch_bounds__(512)
void merge_final_kernel(const float* __restrict__ acc, const float* __restrict__ z,
                        const float* __restrict__ dinv, float* __restrict__ gsum) {
    __shared__ double sdata[8];
    int blk = blockIdx.x;
    int g = blk >> 3, part = blk & 7;
    int c0 = part * 2048 + (int)threadIdx.x * 4;
    int v0 = (g << 14) | c0;
    f32x4 aa = *(const f32x4*)(acc + v0);
    f32x4 zz = *(const f32x4*)(z + v0);
    f32x4 dd = *(const f32x4*)(dinv + v0);
    f32x4 val = dd * (zz + aa);
    double sl = (double)val.x + (double)val.y + (double)val.z + (double)val.w;
    #pragma unroll
    for (int off = 32; off > 0; off >>= 1) sl += __shfl_down(sl, off, 64);
    int wave = threadIdx.x >> 6, lane = threadIdx.x & 63;
    if (lane == 0) sdata[wave] = sl;
    __syncthreads();
    if (threadIdx.x == 0) {
        double tot = 0.0;
        #pragma unroll
        for (int w = 0; w < 8; ++w) tot += sdata[w];
        atomicAdd(&gsum[g], (float)tot);
    }
}

// out[g] = W * gsum[g]/CHUNK + b
__global__ void finalize_kernel(const float* __restrict__ gsum,
                                const float* __restrict__ W, const float* __restrict__ b,
                                float* __restrict__ out) {
    int g = threadIdx.x;
    if (g < N_GRAPHS)
        out[g] = (float)((double)W[0] * ((double)gsum[g] / (double)CHUNK) + (double)b[0]);
}

// ---------------------------------------------------------------------------
// v1 kernels (1024 col-buckets), kept as mid-size-ws fallback.
__global__ __launch_bounds__(TB_SS, 4)
void scatter_sort_kernel(const void* __restrict__ ei,
                         int* __restrict__ cursor, uint32_t* __restrict__ packed) {
    __shared__ uint32_t sorted[EPB_SS];
    __shared__ int h[NBUCKET];
    __shared__ int o[NBUCKET];
    __shared__ int ostart[NBUCKET];
    __shared__ int gbase[NBUCKET];
    __shared__ int s_is64;
    int blk = blockIdx.x, tid = threadIdx.x;
    h[tid] = 0;
    size_t base = (size_t)blk * EPB_SS;
    if (tid < 64) {
        size_t widx = 2 * base + 2 * (size_t)tid * (EPB_SS / 64) + 1;
        int nz = (((const uint32_t*)ei)[widx] != 0u);
        unsigned long long m = __ballot(nz);
        if (tid == 0) s_is64 = (m == 0ull) ? 1 : 0;
    }
    __syncthreads();
    int is64 = s_is64;
    uint32_t c_[EPT];
    if (is64) {
        const unsigned long long* cp = (const unsigned long long*)ei + N_EDGES + base;
        #pragma unroll
        for (int it = 0; it < EPT / 4; ++it) {
            size_t i = (size_t)it * (TB_SS * 4) + (size_t)tid * 4;
            u64x2 a = nt_load_u64x2(cp + i);
            u64x2 b2 = nt_load_u64x2(cp + i + 2);
            c_[it * 4 + 0] = (uint32_t)a.x;  c_[it * 4 + 1] = (uint32_t)a.y;
            c_[it * 4 + 2] = (uint32_t)b2.x; c_[it * 4 + 3] = (uint32_t)b2.y;
            atomicAdd(&h[c_[it * 4 + 0] >> 10], 1);
            atomicAdd(&h[c_[it * 4 + 1] >> 10], 1);
            atomicAdd(&h[c_[it * 4 + 2] >> 10], 1);
            atomicAdd(&h[c_[it * 4 + 3] >> 10], 1);
        }
    } else {
        const uint32_t* cp = (const uint32_t*)ei + N_EDGES + base;
        #pragma unroll
        for (int it = 0; it < EPT / 4; ++it) {
            size_t i = (size_t)it * (TB_SS * 4) + (size_t)tid * 4;
            u32x4 a = nt_load_u32x4(cp + i);
            c_[it * 4 + 0] = a.x; c_[it * 4 + 1] = a.y;
            c_[it * 4 + 2] = a.z; c_[it * 4 + 3] = a.w;
            atomicAdd(&h[a.x >> 10], 1);
            atomicAdd(&h[a.y >> 10], 1);
            atomicAdd(&h[a.z >> 10], 1);
            atomicAdd(&h[a.w >> 10], 1);
        }
    }
    __syncthreads();
    if (tid < 64) {
        int b16 = tid * 16;
        int s = 0;
        #pragma unroll
        for (int j = 0; j < 16; ++j) s += h[b16 + j];
        int v = s;
        #pragma unroll
        for (int off = 1; off < 64; off <<= 1) {
            int up = __shfl_up(v, off, 64);
            if (tid >= off) v += up;
        }
        int run = v - s;
        #pragma unroll
        for (int j = 0; j < 16; ++j) {
            o[b16 + j] = run;
            ostart[b16 + j] = run;
            run += h[b16 + j];
        }
    }
    __syncthreads();
    gbase[tid] = atomicAdd(&cursor[tid], h[tid]);
    if (is64) {
        const unsigned long long* rp = (const unsigned long long*)ei + base;
        #pragma unroll
        for (int it = 0; it < EPT / 4; ++it) {
            size_t i = (size_t)it * (TB_SS * 4) + (size_t)tid * 4;
            u64x2 a = nt_load_u64x2(rp + i);
            u64x2 b2 = nt_load_u64x2(rp + i + 2);
            uint32_t rr[4] = {(uint32_t)a.x, (uint32_t)a.y, (uint32_t)b2.x, (uint32_t)b2.y};
            #pragma unroll
            for (int j = 0; j < 4; ++j) {
                uint32_t c = c_[it * 4 + j];
                int pos = atomicAdd(&o[c >> 10], 1);
                sorted[pos] = (rr[j] << 10) | (c & 1023u);
            }
        }
    } else {
        const uint32_t* rp = (const uint32_t*)ei + base;
        #pragma unroll
        for (int it = 0; it < EPT / 4; ++it) {
            size_t i = (size_t)it * (TB_SS * 4) + (size_t)tid * 4;
            u32x4 a = nt_load_u32x4(rp + i);
            uint32_t rr[4] = {a.x, a.y, a.z, a.w};
            #pragma unroll
            for (int j = 0; j < 4; ++j) {
                uint32_t c = c_[it * 4 + j];
                int pos = atomicAdd(&o[c >> 10], 1);
                sorted[pos] = (rr[j] << 10) | (c & 1023u);
            }
        }
    }
    __syncthreads();
    int wave = tid >> 6, lane = tid & 63;
    for (int k = 0; k < NBUCKET / 16; ++k) {
        int b = wave * (NBUCKET / 16) + k;
        int st = ostart[b];
        int len = o[b] - st;
        int gb = gbase[b];
        if (gb + len > CAP) len = CAP - gb > 0 ? CAP - gb : 0;
        uint32_t* dst = packed + (size_t)b * CAP + gb;
        for (int j = lane; j < len; j += 64)
            dst[j] = sorted[st + j];
    }
}

__global__ __launch_bounds__(512)
void degdinv_kernel(const uint32_t* __restrict__ packed, const int* __restrict__ cursor,
                    const float* __restrict__ x,
                    float* __restrict__ dinv, float* __restrict__ z) {
    __shared__ int h[CPB];
    int b = blockIdx.x, tid = threadIdx.x;
    for (int l = tid; l < CPB; l += 512) h[l] = 0;
    __syncthreads();
    int cnt = cursor[b]; if (cnt > CAP) cnt = CAP;
    const uint32_t* seg = packed + (size_t)b * CAP;
    int nq = cnt >> 2;
    for (int g = tid; g < nq; g += 512) {
        u32x4 v = nt_load_u32x4(seg + 4 * (size_t)g);
        atomicAdd(&h[v.x & 1023u], 1);
        atomicAdd(&h[v.y & 1023u], 1);
        atomicAdd(&h[v.z & 1023u], 1);
        atomicAdd(&h[v.w & 1023u], 1);
    }
    int t = (nq << 2) + tid;
    if (t < cnt) atomicAdd(&h[seg[t] & 1023u], 1);
    __syncthreads();
    for (int l = tid; l < CPB; l += 512) {
        int v = b * CPB + l;
        float d = (float)(1.0 / sqrt((double)(h[l] + 1)));
        dinv[v] = d;
        z[v] = d * x[v];
    }
}

__global__ __launch_bounds__(512)
void hop_kernel(const uint32_t* __restrict__ packed, const int* __restrict__ cursor,
                const float* __restrict__ z, const float* __restrict__ dinv,
                float* __restrict__ out) {
    __shared__ float facc[CPB];
    int b = blockIdx.x, tid = threadIdx.x;
    for (int l = tid; l < CPB; l += 512) facc[l] = 0.0f;
    __syncthreads();
    int cnt = cursor[b]; if (cnt > CAP) cnt = CAP;
    const uint32_t* seg = packed + (size_t)b * CAP;
    int nq = cnt >> 2;
    for (int g = tid; g < nq; g += 512) {
        u32x4 v = nt_load_u32x4(seg + 4 * (size_t)g);
        float z0 = z[v.x >> 10];
        float z1 = z[v.y >> 10];
        float z2 = z[v.z >> 10];
        float z3 = z[v.w >> 10];
        atomicAdd(&facc[v.x & 1023u], z0);
        atomicAdd(&facc[v.y & 1023u], z1);
        atomicAdd(&facc[v.z & 1023u], z2);
        atomicAdd(&facc[v.w & 1023u], z3);
    }
    int t = (nq << 2) + tid;
    if (t < cnt) { uint32_t p = seg[t]; atomicAdd(&facc[p & 1023u], z[p >> 10]); }
    __syncthreads();
    for (int l = tid; l < CPB; l += 512) {
        int v = b * CPB + l;
        float tt = z[v] + facc[l];
        float d = dinv[v];
        out[v] = d * d * tt;
    }
}

__global__ __launch_bounds__(512)
void hop_final_kernel(const uint32_t* __restrict__ packed, const int* __restrict__ cursor,
                      const float* __restrict__ z, const float* __restrict__ dinv,
                      float* __restrict__ gsum) {
    __shared__ float facc[CPB];
    __shared__ double sdata[8];
    int b = blockIdx.x, tid = threadIdx.x;
    for (int l = tid; l < CPB; l += 512) facc[l] = 0.0f;
    __syncthreads();
    int cnt = cursor[b]; if (cnt > CAP) cnt = CAP;
    const uint32_t* seg = packed + (size_t)b * CAP;
    int nq = cnt >> 2;
    for (int g = tid; g < nq; g += 512) {
        u32x4 v = nt_load_u32x4(seg + 4 * (size_t)g);
        float z0 = z[v.x >> 10];
        float z1 = z[v.y >> 10];
        float z2 = z[v.z >> 10];
        float z3 = z[v.w >> 10];
        atomicAdd(&facc[v.x & 1023u], z0);
        atomicAdd(&facc[v.y & 1023u], z1);
        atomicAdd(&facc[v.z & 1023u], z2);
        atomicAdd(&facc[v.w & 1023u], z3);
    }
    int t = (nq << 2) + tid;
    if (t < cnt) { uint32_t p = seg[t]; atomicAdd(&facc[p & 1023u], z[p >> 10]); }
    __syncthreads();
    double s = 0.0;
    for (int l = tid; l < CPB; l += 512) {
        int v = b * CPB + l;
        s += (double)(dinv[v] * (z[v] + facc[l]));
    }
    #pragma unroll
    for (int off = 32; off > 0; off >>= 1) s += __shfl_down(s, off, 64);
    int wave = tid >> 6, lane = tid & 63;
    if (lane == 0) sdata[wave] = s;
    __syncthreads();
    if (tid == 0) {
        double tot = 0.0;
        #pragma unroll
        for (int w = 0; w < 8; ++w) tot += sdata[w];
        atomicAdd(&gsum[b >> 4], (float)tot);
    }
}

// ---------------- fallback (push, atomics) for small ws ---------------------
__global__ void detect_kernel(const uint32_t* __restrict__ ei, int* __restrict__ flag) {
    __shared__ int any_nz;
    if (threadIdx.x == 0) any_nz = 0;
    __syncthreads();
    int nz = 0;
    for (int i = threadIdx.x; i < 32768; i += blockDim.x)
        nz |= (ei[2 * i + 1] != 0u);
    if (nz) atomicOr(&any_nz, 1);
    __syncthreads();
    if (threadIdx.x == 0) flag[0] = any_nz ? 0 : 1;
}

__global__ void zero_int_kernel(int* __restrict__ p) {
    int i = blockIdx.x * blockDim.x + threadIdx.x;
    p[i] = 0;
}

__device__ __forceinline__ int load_idx(const void* ei, int is64, size_t pos) {
    if (is64) return (int)((const unsigned long long*)ei)[pos];
    return ((const int*)ei)[pos];
}

__global__ void count_kernel(const void* __restrict__ ei, const int* __restrict__ flag,
                             int* __restrict__ deg) {
    int e = blockIdx.x * blockDim.x + threadIdx.x;
    int c = load_idx(ei, flag[0], (size_t)N_EDGES + (size_t)e);
    atomicAdd(&deg[c], 1);
}

__global__ void dinv_kernel(const int* __restrict__ deg, float* __restrict__ dinv) {
    int v = blockIdx.x * blockDim.x + threadIdx.x;
    dinv[v] = (float)(1.0 / sqrt((double)(deg[v] + 1)));
}

__global__ void prep_first2_kernel(const float* __restrict__ x, const float* __restrict__ dinv,
                                   float* __restrict__ z, float* __restrict__ acc) {
    int v = blockIdx.x * blockDim.x + threadIdx.x;
    float t = dinv[v] * x[v];
    z[v] = t;
    acc[v] = t;
}

__global__ void prep_mid_kernel(const float* __restrict__ dinv,
                                float* __restrict__ z, float* __restrict__ acc) {
    int v = blockIdx.x * blockDim.x + threadIdx.x;
    float d = dinv[v];
    float t = d * d * acc[v];
    z[v] = t;
    acc[v] = t;
}

__global__ void push_kernel(const void* __restrict__ ei, const int* __restrict__ flag,
                            const float* __restrict__ z, float* __restrict__ acc) {
    int e = blockIdx.x * blockDim.x + threadIdx.x;
    int is64 = flag[0];
    int r, c;
    if (is64) {
        const unsigned long long* p = (const unsigned long long*)ei;
        r = (int)p[e];
        c = (int)p[(size_t)N_EDGES + (size_t)e];
    } else {
        const int* p = (const int*)ei;
        r = p[e];
        c = p[(size_t)N_EDGES + (size_t)e];
    }
    __hip_atomic_fetch_add(&acc[c], z[r], __ATOMIC_RELAXED, __HIP_MEMORY_SCOPE_AGENT);
}

__global__ void final_scale_kernel(const float* __restrict__ dinv,
                                   const float* __restrict__ acc, float* __restrict__ xf) {
    int v = blockIdx.x * blockDim.x + threadIdx.x;
    xf[v] = dinv[v] * acc[v];
}

__global__ void pool_kernel(const float* __restrict__ xf,
                            const float* __restrict__ W, const float* __restrict__ b,
                            float* __restrict__ out) {
    __shared__ double sdata[256];
    int g = blockIdx.x;
    int base = g * CHUNK;
    double s = 0.0;
    for (int i = threadIdx.x; i < CHUNK; i += 256) s += (double)xf[base + i];
    sdata[threadIdx.x] = s;
    __syncthreads();
    for (int off = 128; off > 0; off >>= 1) {
        if (threadIdx.x < off) sdata[threadIdx.x] += sdata[threadIdx.x + off];
        __syncthreads();
    }
    if (threadIdx.x == 0)
        out[g] = (float)((double)W[0] * (sdata[0] / (double)CHUNK) + (double)b[0]);
}

extern "C" void kernel_launch(void* const* d_in, const int* in_sizes, int n_in,
                              void* d_out, int out_size, void* d_ws, size_t ws_size,
                              hipStream_t stream) {
    const float* x = (const float*)d_in[0];
    const void*  ei = d_in[1];
    const float* W = (const float*)d_in[2];
    const float* b = (const float*)d_in[3];
    float* out = (float*)d_out;

    char* ws = (char*)d_ws;
    const size_t MB4 = 4ull << 20;
    const size_t packed_sz = (size_t)NTILE * CAP * 4;            // 72 MB

    // v3 layout
    size_t off_cursor = 0;                       // 4 KB (1024 tiles)
    size_t off_gsum   = 4096;                    // 256 B
    size_t off_deg    = 8192;                    // 4 MB
    size_t off_acc    = off_deg + MB4;           // 4 MB
    size_t off_dinv   = off_acc + MB4;           // 4 MB
    size_t off_za     = off_dinv + MB4;          // 4 MB
    size_t off_zb     = off_za + MB4;            // 4 MB
    size_t off_packed3 = off_zb + MB4;           // 72 MB
    size_t needed_v3  = off_packed3 + packed_sz; // ~92 MB

    // v1 layout
    size_t off1_gsum   = NBUCKET * 4;
    size_t off1_dinv   = off1_gsum + 256;
    size_t off1_za     = off1_dinv + MB4;
    size_t off1_zb     = off1_za + MB4;
    size_t off1_packed = off1_zb + MB4;
    size_t needed_v1   = off1_packed + packed_sz; // ~84 MB

    const int TB = 256;

    if (ws_size >= needed_v3) {
        int*      cursor = (int*)(ws + off_cursor);
        float*    gsum   = (float*)(ws + off_gsum);
        int*      deg    = (int*)(ws + off_deg);
        float*    acc    = (float*)(ws + off_acc);
        float*    dinv   = (float*)(ws + off_dinv);
        float*    za     = (float*)(ws + off_za);
        float*    zb     = (float*)(ws + off_zb);
        uint32_t* packed = (uint32_t*)(ws + off_packed3);

        // zero cursor + gsum + deg + acc in one async memset
        hipMemsetAsync(ws, 0, off_acc + MB4, stream);

        tile_sort_kernel<<<NBLK_SS, TB_SS, 0, stream>>>(ei, cursor, packed);
        tile_rowsort_kernel<<<NTILE, 512, 0, stream>>>(packed, cursor, deg);
        dinvz_kernel<<<N_NODES / 2048, 512, 0, stream>>>(deg, x, dinv, za);

        hop_acc_kernel<<<NTILE, 512, 0, stream>>>(packed, cursor, za, acc);
        merge_mid_kernel<<<N_NODES / 2048, 512, 0, stream>>>(acc, za, dinv, zb);

        hop_acc_kernel<<<NTILE, 512, 0, stream>>>(packed, cursor, zb, acc);
        merge_mid_kernel<<<N_NODES / 2048, 512, 0, stream>>>(acc, zb, dinv, za);

        hop_acc_kernel<<<NTILE, 512, 0, stream>>>(packed, cursor, za, acc);
        merge_mid_kernel<<<N_NODES / 2048, 512, 0, stream>>>(acc, za, dinv, zb);

        hop_acc_kernel<<<NTILE, 512, 0, stream>>>(packed, cursor, zb, acc);
        merge_final_kernel<<<N_GRAPHS * 8, 512, 0, stream>>>(acc, zb, dinv, gsum);

        finalize_kernel<<<1, 64, 0, stream>>>(gsum, W, b, out);
    } else if (ws_size >= needed_v1) {
        int*      cursor = (int*)(ws);
        float*    gsum   = (float*)(ws + off1_gsum);
        float*    dinv   = (float*)(ws + off1_dinv);
        float*    za     = (float*)(ws + off1_za);
        float*    zb     = (float*)(ws + off1_zb);
        uint32_t* packed = (uint32_t*)(ws + off1_packed);

        hipMemsetAsync(ws, 0, NBUCKET * 4 + 256, stream);

        scatter_sort_kernel<<<NBLK_SS, TB_SS, 0, stream>>>(ei, cursor, packed);
        degdinv_kernel<<<NBUCKET, 512, 0, stream>>>(packed, cursor, x, dinv, za);

        hop_kernel<<<NBUCKET, 512, 0, stream>>>(packed, cursor, za, dinv, zb);
        hop_kernel<<<NBUCKET, 512, 0, stream>>>(packed, cursor, zb, dinv, za);
        hop_kernel<<<NBUCKET, 512, 0, stream>>>(packed, cursor, za, dinv, zb);
        hop_final_kernel<<<NBUCKET, 512, 0, stream>>>(packed, cursor, zb, dinv, gsum);

        finalize_kernel<<<1, 64, 0, stream>>>(gsum, W, b, out);
    } else {
        // Fallback: push-based with atomics.
        int*   flag = (int*)ws;
        float* dinv = (float*)(ws + 256);
        float* za   = (float*)(ws + 256 + MB4);
        float* zb   = (float*)(ws + 256 + 2 * MB4);
        int*   deg  = (int*)(ws + 256 + 3 * MB4);

        detect_kernel<<<1, TB, 0, stream>>>((const uint32_t*)ei, flag);
        zero_int_kernel<<<N_NODES / TB, TB, 0, stream>>>(deg);
        count_kernel<<<N_EDGES / TB, TB, 0, stream>>>(ei, flag, deg);
        dinv_kernel<<<N_NODES / TB, TB, 0, stream>>>(deg, dinv);

        prep_first2_kernel<<<N_NODES / TB, TB, 0, stream>>>(x, dinv, za, zb);
        push_kernel<<<N_EDGES / TB, TB, 0, stream>>>(ei, flag, za, zb);
        for (int h = 1; h < K_HOPS; ++h) {
            prep_mid_kernel<<<N_NODES / TB, TB, 0, stream>>>(dinv, za, zb);
            push_kernel<<<N_EDGES / TB, TB, 0, stream>>>(ei, flag, za, zb);
        }
        final_scale_kernel<<<N_NODES / TB, TB, 0, stream>>>(dinv, zb, za);
        pool_kernel<<<N_GRAPHS, TB, 0, stream>>>(za, W, b, out);
    }
}